// Round 8
// baseline (237.308 us; speedup 1.0000x reference)
//
#include <hip/hip_runtime.h>
#include <hip/hip_cooperative_groups.h>
#include <math.h>

namespace cg = cooperative_groups;

#define NTOK 8192
#define DIMV 512
#define CD 13
#define KSZ 8192
#define NPARTS 512            /* blocks == partial-C count                  */
#define TPB 16                /* tokens per block                           */

/* d_ws layout:
   [0, 16MB)        ws_C  : NPARTS x 8192 partial C
   [+0, +4KB)       ws_pc : 512 x {cm, pe}
   [+4KB, +2KB)     ws_e  : 512 entropy partials                            */
#define C_BYTES  ((size_t)NPARTS * KSZ * 4)
#define PC_OFF   C_BYTES
#define E_OFF    (PC_OFF + 4096)

// ===========================================================================
// MEGA (cooperative): phase A+B per block (16 tokens: proj, ind, out, cm/pe,
// factors, partial-C) -> grid.sync -> phase C (16 slots reduced over 512
// partials + entropy partial) -> grid.sync -> phase D (block 0 final).
// ===========================================================================
__global__ __launch_bounds__(256) void mega(const float* __restrict__ x,
                                            const float* __restrict__ w_in,
                                            const float* __restrict__ b_in,
                                            const float* __restrict__ w_out,
                                            const float* __restrict__ b_out,
                                            float* __restrict__ ws_C,
                                            float* __restrict__ ws_pc,
                                            float* __restrict__ ws_e,
                                            float* __restrict__ outv,
                                            float* __restrict__ out_ind,
                                            float* __restrict__ d_aux) {
  __shared__ __align__(16) float s_winT[CD * DIMV];  // [c][d], transposed
  __shared__ float sh[TPB][CD];                      // h per token
  __shared__ __align__(16) float sA[TPB][2][32];     // [tok][khi&1][khi>>1]
  __shared__ __align__(16) float sB[TPB][128];       // [tok][klo]
  __shared__ float s_cm[16], s_pe[16];
  __shared__ __align__(16) float4 sred4[256];        // phase C reduce
  __shared__ float rc[256], rp[256], re[256];        // phase D
  cg::grid_group grid = cg::this_grid();
  int t = threadIdx.x;

  // ---------------- phase A: projection & epilogue ----------------
  for (int d = t; d < DIMV; d += 256) {
#pragma unroll
    for (int c = 0; c < CD; ++c) s_winT[c * DIMV + d] = w_in[d * CD + c];
  }
  __syncthreads();

  int lane = t & 63;
  int wave = t >> 6;
  int l15 = lane & 15;
  int grp = lane >> 4;
  int tok = wave * 4 + grp;
  int n = blockIdx.x * TPB + tok;

  const float4* x4 = (const float4*)(x + (size_t)n * DIMV);
  float facc[CD];
#pragma unroll
  for (int c = 0; c < CD; ++c) facc[c] = 0.f;
#pragma unroll
  for (int j = 0; j < 8; ++j) {
    float4 xv = x4[l15 + j * 16];
    int dbase = (l15 + j * 16) * 4;
#pragma unroll
    for (int c = 0; c < CD; ++c) {
      const float4 wv = *(const float4*)&s_winT[c * DIMV + dbase];
      facc[c] += xv.x * wv.x + xv.y * wv.y + xv.z * wv.z + xv.w * wv.w;
    }
  }
  double acc[CD];
#pragma unroll
  for (int c = 0; c < CD; ++c) {
    double a = (double)facc[c];
    a += __shfl_xor(a, 1, 64);
    a += __shfl_xor(a, 2, 64);
    a += __shfl_xor(a, 4, 64);
    a += __shfl_xor(a, 8, 64);
    acc[c] = a + (double)b_in[c];
  }

  int idx = 0;
#pragma unroll
  for (int c = 0; c < CD; ++c) idx |= (acc[c] > 0.0 ? 1 : 0) << (12 - c);
  if (l15 == 0) out_ind[n] = (float)idx;

  float hv = 0.f;
#pragma unroll
  for (int c = 0; c < CD; ++c) if (l15 == c) hv = (float)acc[c];
  float cm = 0.f, pe = 0.f;
  if (l15 < CD) {
    sh[tok][l15] = hv;
    float a = fabsf(hv);
    float d1 = a - 1.f;
    cm = d1 * d1;
    float z = 4.f * a;
    float e = expf(-z);
    pe = log1pf(e) + z * e / (1.f + e);
  }
  cm += __shfl_xor(cm, 1, 64); pe += __shfl_xor(pe, 1, 64);
  cm += __shfl_xor(cm, 2, 64); pe += __shfl_xor(pe, 2, 64);
  cm += __shfl_xor(cm, 4, 64); pe += __shfl_xor(pe, 4, 64);
  cm += __shfl_xor(cm, 8, 64); pe += __shfl_xor(pe, 8, 64);
  if (l15 == 0) { s_cm[tok] = cm; s_pe[tok] = pe; }

  // out = sign(h) @ w_out + b_out; c-outer, w_out from L2 serves 4 tokens
  int dpos = lane * 4;
  int id2[4];
#pragma unroll
  for (int tt = 0; tt < 4; ++tt) id2[tt] = __shfl(idx, tt * 16, 64);
  float4 o[4][2];
  {
    float4 bo0 = *(const float4*)(b_out + dpos);
    float4 bo1 = *(const float4*)(b_out + dpos + 256);
#pragma unroll
    for (int tt = 0; tt < 4; ++tt) { o[tt][0] = bo0; o[tt][1] = bo1; }
  }
#pragma unroll
  for (int c = 0; c < CD; ++c) {
    const float4 w0 = *(const float4*)&w_out[c * DIMV + dpos];
    const float4 w1 = *(const float4*)&w_out[c * DIMV + dpos + 256];
#pragma unroll
    for (int tt = 0; tt < 4; ++tt) {
      float sgn = ((id2[tt] >> (12 - c)) & 1) ? 1.f : -1.f;
      o[tt][0].x = fmaf(sgn, w0.x, o[tt][0].x);
      o[tt][0].y = fmaf(sgn, w0.y, o[tt][0].y);
      o[tt][0].z = fmaf(sgn, w0.z, o[tt][0].z);
      o[tt][0].w = fmaf(sgn, w0.w, o[tt][0].w);
      o[tt][1].x = fmaf(sgn, w1.x, o[tt][1].x);
      o[tt][1].y = fmaf(sgn, w1.y, o[tt][1].y);
      o[tt][1].z = fmaf(sgn, w1.z, o[tt][1].z);
      o[tt][1].w = fmaf(sgn, w1.w, o[tt][1].w);
    }
  }
  int n0 = blockIdx.x * TPB + wave * 4;
#pragma unroll
  for (int tt = 0; tt < 4; ++tt) {
    float4* dst = (float4*)(outv + (size_t)(n0 + tt) * DIMV);
    dst[lane] = o[tt][0];
    dst[lane + 64] = o[tt][1];
  }

  __syncthreads();
  if (t == 0) {
    float C = 0.f, P = 0.f;
#pragma unroll
    for (int i = 0; i < 16; ++i) { C += s_cm[i]; P += s_pe[i]; }
    ws_pc[blockIdx.x * 2] = C;
    ws_pc[blockIdx.x * 2 + 1] = P;
  }

  // ---------------- phase B: factors + 16-token partial C ----------------
  for (int m = wave; m < TPB; m += 4) {
    float p[CD], q[CD];
#pragma unroll
    for (int c = 0; c < CD; ++c) {
      float hvv = sh[m][c];
      float e = expf(-4.f * hvv);
      float r = 1.f / (1.f + e);
      p[c] = r;
      q[c] = e * r;
    }
    float A = ((lane >> 5) & 1) ? p[0] : q[0];
    A *= ((lane >> 4) & 1) ? p[1] : q[1];
    A *= ((lane >> 3) & 1) ? p[2] : q[2];
    A *= ((lane >> 2) & 1) ? p[3] : q[3];
    A *= ((lane >> 1) & 1) ? p[4] : q[4];
    A *= (lane & 1) ? p[5] : q[5];
    sA[m][lane & 1][lane >> 1] = A;
    float Bb = ((lane >> 5) & 1) ? p[7] : q[7];
    Bb *= ((lane >> 4) & 1) ? p[8] : q[8];
    Bb *= ((lane >> 3) & 1) ? p[9] : q[9];
    Bb *= ((lane >> 2) & 1) ? p[10] : q[10];
    Bb *= ((lane >> 1) & 1) ? p[11] : q[11];
    Bb *= (lane & 1) ? p[12] : q[12];
    sB[m][lane] = q[6] * Bb;
    sB[m][64 + lane] = p[6] * Bb;
  }
  __syncthreads();

  int c2 = t >> 7;
  int klo = t & 127;
  float acc2[32];
#pragma unroll
  for (int j = 0; j < 32; ++j) acc2[j] = 0.f;
  for (int m = 0; m < TPB; ++m) {
    float Bv = sB[m][klo];
    const float4* A4 = (const float4*)&sA[m][c2][0];  // wave-uniform
#pragma unroll
    for (int jj = 0; jj < 8; ++jj) {
      float4 a = A4[jj];
      acc2[jj * 4 + 0] = fmaf(a.x, Bv, acc2[jj * 4 + 0]);
      acc2[jj * 4 + 1] = fmaf(a.y, Bv, acc2[jj * 4 + 1]);
      acc2[jj * 4 + 2] = fmaf(a.z, Bv, acc2[jj * 4 + 2]);
      acc2[jj * 4 + 3] = fmaf(a.w, Bv, acc2[jj * 4 + 3]);
    }
  }
  {
    float* dst = ws_C + (size_t)blockIdx.x * KSZ;
#pragma unroll
    for (int j = 0; j < 32; ++j) dst[t + 256 * j] = acc2[j];  // coalesced
  }

  __threadfence();
  grid.sync();

  // ---------------- phase C: reduce 16 slots over 512 partials ----------
  {
    int jb = blockIdx.x;          // slot group: slots [jb*16, jb*16+16)
    int q = t & 3;
    int pg = t >> 2;              // 0..63
    float4 a0 = {0.f, 0.f, 0.f, 0.f}, a1 = {0.f, 0.f, 0.f, 0.f};
    size_t off = (size_t)jb * 16 + q * 4;
    for (int i = 0; i < 8; i += 2) {
      const float4 v0 = *(const float4*)(ws_C + (size_t)(pg + 64 * i) * KSZ + off);
      const float4 v1 = *(const float4*)(ws_C + (size_t)(pg + 64 * (i + 1)) * KSZ + off);
      a0.x += v0.x; a0.y += v0.y; a0.z += v0.z; a0.w += v0.w;
      a1.x += v1.x; a1.y += v1.y; a1.z += v1.z; a1.w += v1.w;
    }
    a0.x += a1.x; a0.y += a1.y; a0.z += a1.z; a0.w += a1.w;
    sred4[t] = a0;                // sred4[pg*4+q] == sred4[t]
    __syncthreads();
#pragma unroll
    for (int offr = 32; offr >= 1; offr >>= 1) {
      if ((t >> 2) < offr) {
        float4 b = sred4[t + offr * 4];
        float4 a = sred4[t];
        a.x += b.x; a.y += b.y; a.z += b.z; a.w += b.w;
        sred4[t] = a;
      }
      __syncthreads();
    }
    float contrib = 0.f;
    if (t < 16) {
      float v = ((const float*)sred4)[t];
      float avg = v * (1.f / (float)NTOK);
      contrib = -avg * logf(avg + 1e-5f);
    }
    if (t < 64) {
      contrib += __shfl_xor(contrib, 1, 64);
      contrib += __shfl_xor(contrib, 2, 64);
      contrib += __shfl_xor(contrib, 4, 64);
      contrib += __shfl_xor(contrib, 8, 64);
      if (t == 0) ws_e[jb] = contrib;
    }
  }

  __threadfence();
  grid.sync();

  // ---------------- phase D: final assembly (block 0) ----------------
  if (blockIdx.x == 0) {
    float cm2 = 0.f, pe2 = 0.f;
    for (int i = t; i < 512; i += 256) { cm2 += ws_pc[2 * i]; pe2 += ws_pc[2 * i + 1]; }
    rc[t] = cm2; rp[t] = pe2; re[t] = ws_e[t] + ws_e[t + 256];
    __syncthreads();
    if (t < 64) {
      float C = rc[t] + rc[t + 64] + rc[t + 128] + rc[t + 192];
      float P = rp[t] + rp[t + 64] + rp[t + 128] + rp[t + 192];
      float E = re[t] + re[t + 64] + re[t + 128] + re[t + 192];
      C += __shfl_xor(C, 1, 64); P += __shfl_xor(P, 1, 64); E += __shfl_xor(E, 1, 64);
      C += __shfl_xor(C, 2, 64); P += __shfl_xor(P, 2, 64); E += __shfl_xor(E, 2, 64);
      C += __shfl_xor(C, 4, 64); P += __shfl_xor(P, 4, 64); E += __shfl_xor(E, 4, 64);
      C += __shfl_xor(C, 8, 64); P += __shfl_xor(P, 8, 64); E += __shfl_xor(E, 8, 64);
      C += __shfl_xor(C, 16, 64); P += __shfl_xor(P, 16, 64); E += __shfl_xor(E, 16, 64);
      C += __shfl_xor(C, 32, 64); P += __shfl_xor(P, 32, 64); E += __shfl_xor(E, 32, 64);
      if (t == 0) {
        float commit = C * (1.f / (float)(NTOK * CD));
        float psE = P * (1.f / (float)NTOK);
        d_aux[0] = 0.1f * (psE - E) + 0.25f * commit;
      }
    }
  }
}

// ===========================================================================
// Fallback path (R6's proven 3-dispatch pipeline), used only if cooperative
// launch is unavailable.
// ===========================================================================
__global__ __launch_bounds__(256) void ka_fused(const float* __restrict__ x,
                                                const float* __restrict__ w_in,
                                                const float* __restrict__ b_in,
                                                const float* __restrict__ w_out,
                                                const float* __restrict__ b_out,
                                                float* __restrict__ ws_C,
                                                float* __restrict__ ws_pc,
                                                float* __restrict__ outv,
                                                float* __restrict__ out_ind) {
  __shared__ __align__(16) float s_winT[CD * DIMV];
  __shared__ float sh[TPB][CD];
  __shared__ __align__(16) float sA[TPB][2][32];
  __shared__ __align__(16) float sB[TPB][128];
  __shared__ float s_cm[16], s_pe[16];
  int t = threadIdx.x;
  for (int d = t; d < DIMV; d += 256) {
#pragma unroll
    for (int c = 0; c < CD; ++c) s_winT[c * DIMV + d] = w_in[d * CD + c];
  }
  __syncthreads();
  int lane = t & 63, wave = t >> 6, l15 = lane & 15, grp = lane >> 4;
  int tok = wave * 4 + grp;
  int n = blockIdx.x * TPB + tok;
  const float4* x4 = (const float4*)(x + (size_t)n * DIMV);
  float facc[CD];
#pragma unroll
  for (int c = 0; c < CD; ++c) facc[c] = 0.f;
#pragma unroll
  for (int j = 0; j < 8; ++j) {
    float4 xv = x4[l15 + j * 16];
    int dbase = (l15 + j * 16) * 4;
#pragma unroll
    for (int c = 0; c < CD; ++c) {
      const float4 wv = *(const float4*)&s_winT[c * DIMV + dbase];
      facc[c] += xv.x * wv.x + xv.y * wv.y + xv.z * wv.z + xv.w * wv.w;
    }
  }
  double acc[CD];
#pragma unroll
  for (int c = 0; c < CD; ++c) {
    double a = (double)facc[c];
    a += __shfl_xor(a, 1, 64);
    a += __shfl_xor(a, 2, 64);
    a += __shfl_xor(a, 4, 64);
    a += __shfl_xor(a, 8, 64);
    acc[c] = a + (double)b_in[c];
  }
  int idx = 0;
#pragma unroll
  for (int c = 0; c < CD; ++c) idx |= (acc[c] > 0.0 ? 1 : 0) << (12 - c);
  if (l15 == 0) out_ind[n] = (float)idx;
  float hv = 0.f;
#pragma unroll
  for (int c = 0; c < CD; ++c) if (l15 == c) hv = (float)acc[c];
  float cm = 0.f, pe = 0.f;
  if (l15 < CD) {
    sh[tok][l15] = hv;
    float a = fabsf(hv);
    float d1 = a - 1.f;
    cm = d1 * d1;
    float z = 4.f * a;
    float e = expf(-z);
    pe = log1pf(e) + z * e / (1.f + e);
  }
  cm += __shfl_xor(cm, 1, 64); pe += __shfl_xor(pe, 1, 64);
  cm += __shfl_xor(cm, 2, 64); pe += __shfl_xor(pe, 2, 64);
  cm += __shfl_xor(cm, 4, 64); pe += __shfl_xor(pe, 4, 64);
  cm += __shfl_xor(cm, 8, 64); pe += __shfl_xor(pe, 8, 64);
  if (l15 == 0) { s_cm[tok] = cm; s_pe[tok] = pe; }
  int dpos = lane * 4;
  int id2[4];
#pragma unroll
  for (int tt = 0; tt < 4; ++tt) id2[tt] = __shfl(idx, tt * 16, 64);
  float4 o[4][2];
  {
    float4 bo0 = *(const float4*)(b_out + dpos);
    float4 bo1 = *(const float4*)(b_out + dpos + 256);
#pragma unroll
    for (int tt = 0; tt < 4; ++tt) { o[tt][0] = bo0; o[tt][1] = bo1; }
  }
#pragma unroll
  for (int c = 0; c < CD; ++c) {
    const float4 w0 = *(const float4*)&w_out[c * DIMV + dpos];
    const float4 w1 = *(const float4*)&w_out[c * DIMV + dpos + 256];
#pragma unroll
    for (int tt = 0; tt < 4; ++tt) {
      float sgn = ((id2[tt] >> (12 - c)) & 1) ? 1.f : -1.f;
      o[tt][0].x = fmaf(sgn, w0.x, o[tt][0].x);
      o[tt][0].y = fmaf(sgn, w0.y, o[tt][0].y);
      o[tt][0].z = fmaf(sgn, w0.z, o[tt][0].z);
      o[tt][0].w = fmaf(sgn, w0.w, o[tt][0].w);
      o[tt][1].x = fmaf(sgn, w1.x, o[tt][1].x);
      o[tt][1].y = fmaf(sgn, w1.y, o[tt][1].y);
      o[tt][1].z = fmaf(sgn, w1.z, o[tt][1].z);
      o[tt][1].w = fmaf(sgn, w1.w, o[tt][1].w);
    }
  }
  int n0 = blockIdx.x * TPB + wave * 4;
#pragma unroll
  for (int tt = 0; tt < 4; ++tt) {
    float4* dst = (float4*)(outv + (size_t)(n0 + tt) * DIMV);
    dst[lane] = o[tt][0];
    dst[lane + 64] = o[tt][1];
  }
  __syncthreads();
  if (t == 0) {
    float C = 0.f, P = 0.f;
#pragma unroll
    for (int i = 0; i < 16; ++i) { C += s_cm[i]; P += s_pe[i]; }
    ws_pc[blockIdx.x * 2] = C;
    ws_pc[blockIdx.x * 2 + 1] = P;
  }
  for (int m = wave; m < TPB; m += 4) {
    float p[CD], q[CD];
#pragma unroll
    for (int c = 0; c < CD; ++c) {
      float hvv = sh[m][c];
      float e = expf(-4.f * hvv);
      float r = 1.f / (1.f + e);
      p[c] = r; q[c] = e * r;
    }
    float A = ((lane >> 5) & 1) ? p[0] : q[0];
    A *= ((lane >> 4) & 1) ? p[1] : q[1];
    A *= ((lane >> 3) & 1) ? p[2] : q[2];
    A *= ((lane >> 2) & 1) ? p[3] : q[3];
    A *= ((lane >> 1) & 1) ? p[4] : q[4];
    A *= (lane & 1) ? p[5] : q[5];
    sA[m][lane & 1][lane >> 1] = A;
    float Bb = ((lane >> 5) & 1) ? p[7] : q[7];
    Bb *= ((lane >> 4) & 1) ? p[8] : q[8];
    Bb *= ((lane >> 3) & 1) ? p[9] : q[9];
    Bb *= ((lane >> 2) & 1) ? p[10] : q[10];
    Bb *= ((lane >> 1) & 1) ? p[11] : q[11];
    Bb *= (lane & 1) ? p[12] : q[12];
    sB[m][lane] = q[6] * Bb;
    sB[m][64 + lane] = p[6] * Bb;
  }
  __syncthreads();
  int c2 = t >> 7;
  int klo = t & 127;
  float acc2[32];
#pragma unroll
  for (int j = 0; j < 32; ++j) acc2[j] = 0.f;
  for (int m = 0; m < TPB; ++m) {
    float Bv = sB[m][klo];
    const float4* A4 = (const float4*)&sA[m][c2][0];
#pragma unroll
    for (int jj = 0; jj < 8; ++jj) {
      float4 a = A4[jj];
      acc2[jj * 4 + 0] = fmaf(a.x, Bv, acc2[jj * 4 + 0]);
      acc2[jj * 4 + 1] = fmaf(a.y, Bv, acc2[jj * 4 + 1]);
      acc2[jj * 4 + 2] = fmaf(a.z, Bv, acc2[jj * 4 + 2]);
      acc2[jj * 4 + 3] = fmaf(a.w, Bv, acc2[jj * 4 + 3]);
    }
  }
  float* dst = ws_C + (size_t)blockIdx.x * KSZ;
#pragma unroll
  for (int j = 0; j < 32; ++j) dst[t + 256 * j] = acc2[j];
}

__global__ __launch_bounds__(256) void kb_cbent(const float* __restrict__ ws_C,
                                                float* __restrict__ ws_e) {
  __shared__ float red[256];
  int t = threadIdx.x;
  int sl = t & 31, pg = t >> 5;
  int s = blockIdx.x * 32 + sl;
  float a0 = 0.f, a1 = 0.f, a2 = 0.f, a3 = 0.f;
  for (int i = 0; i < 64; i += 4) {
    a0 += ws_C[(size_t)(pg + 8 * (i + 0)) * KSZ + s];
    a1 += ws_C[(size_t)(pg + 8 * (i + 1)) * KSZ + s];
    a2 += ws_C[(size_t)(pg + 8 * (i + 2)) * KSZ + s];
    a3 += ws_C[(size_t)(pg + 8 * (i + 3)) * KSZ + s];
  }
  red[t] = (a0 + a1) + (a2 + a3);
  __syncthreads();
  float contrib = 0.f;
  if (t < 32) {
    float v = red[t];
#pragma unroll
    for (int j = 1; j < 8; ++j) v += red[t + 32 * j];
    float avg = v * (1.f / (float)NTOK);
    contrib = -avg * logf(avg + 1e-5f);
  }
  if (t < 64) {
    contrib += __shfl_xor(contrib, 1, 64);
    contrib += __shfl_xor(contrib, 2, 64);
    contrib += __shfl_xor(contrib, 4, 64);
    contrib += __shfl_xor(contrib, 8, 64);
    contrib += __shfl_xor(contrib, 16, 64);
    if (t == 0) ws_e[blockIdx.x] = contrib;
  }
}

__global__ __launch_bounds__(256) void kc_final(const float* __restrict__ ws_pc,
                                                const float* __restrict__ ws_e,
                                                float* __restrict__ d_aux) {
  __shared__ float rc[256], rp[256], re[256];
  int t = threadIdx.x;
  float cm = 0.f, pe = 0.f;
  for (int i = t; i < 512; i += 256) { cm += ws_pc[2 * i]; pe += ws_pc[2 * i + 1]; }
  rc[t] = cm; rp[t] = pe; re[t] = ws_e[t];
  __syncthreads();
  if (t < 64) {
    float C = rc[t] + rc[t + 64] + rc[t + 128] + rc[t + 192];
    float P = rp[t] + rp[t + 64] + rp[t + 128] + rp[t + 192];
    float E = re[t] + re[t + 64] + re[t + 128] + re[t + 192];
    C += __shfl_xor(C, 1, 64); P += __shfl_xor(P, 1, 64); E += __shfl_xor(E, 1, 64);
    C += __shfl_xor(C, 2, 64); P += __shfl_xor(P, 2, 64); E += __shfl_xor(E, 2, 64);
    C += __shfl_xor(C, 4, 64); P += __shfl_xor(P, 4, 64); E += __shfl_xor(E, 4, 64);
    C += __shfl_xor(C, 8, 64); P += __shfl_xor(P, 8, 64); E += __shfl_xor(E, 8, 64);
    C += __shfl_xor(C, 16, 64); P += __shfl_xor(P, 16, 64); E += __shfl_xor(E, 16, 64);
    C += __shfl_xor(C, 32, 64); P += __shfl_xor(P, 32, 64); E += __shfl_xor(E, 32, 64);
    if (t == 0) {
      float commit = C * (1.f / (float)(NTOK * CD));
      float psE = P * (1.f / (float)NTOK);
      d_aux[0] = 0.1f * (psE - E) + 0.25f * commit;
    }
  }
}

extern "C" void kernel_launch(void* const* d_in, const int* in_sizes, int n_in,
                              void* d_out, int out_size, void* d_ws, size_t ws_size,
                              hipStream_t stream) {
  const float* x     = (const float*)d_in[0];
  const float* w_in  = (const float*)d_in[1];
  const float* b_in  = (const float*)d_in[2];
  const float* w_out = (const float*)d_in[3];
  const float* b_out = (const float*)d_in[4];

  float* outv = (float*)d_out;                       // [4*2048*512]
  float* ind  = outv + (size_t)NTOK * DIMV;          // [8192] as float
  float* aux  = ind + NTOK;                          // [1]

  float* ws_C  = (float*)d_ws;
  float* ws_pc = (float*)((char*)d_ws + PC_OFF);
  float* ws_e  = (float*)((char*)d_ws + E_OFF);

  void* args[] = {(void*)&x, (void*)&w_in, (void*)&b_in, (void*)&w_out,
                  (void*)&b_out, (void*)&ws_C, (void*)&ws_pc, (void*)&ws_e,
                  (void*)&outv, (void*)&ind, (void*)&aux};
  hipError_t err = hipLaunchCooperativeKernel(reinterpret_cast<void*>(mega),
                                              dim3(NPARTS), dim3(256),
                                              args, 0, stream);
  if (err != hipSuccess) {
    (void)hipGetLastError();  // clear error, fall back to 3-dispatch path
    ka_fused<<<NPARTS, 256, 0, stream>>>(x, w_in, b_in, w_out, b_out,
                                         ws_C, ws_pc, outv, ind);
    kb_cbent<<<256, 256, 0, stream>>>(ws_C, ws_e);
    kc_final<<<1, 256, 0, stream>>>(ws_pc, ws_e, aux);
  }
}

// Round 9
// 43.219 us; speedup vs baseline: 5.4909x; 5.4909x over previous
//
#include <hip/hip_runtime.h>
#include <math.h>

#define NTOK 8192
#define DIMV 512
#define CD 13
#define KSZ 8192
#define NPARTS 512            /* KA blocks == partial-C count               */
#define TPB 16                /* tokens per KA block                        */

/* d_ws layout:
   [0, 16MB)          ws_C   : NPARTS x 8192 partial C
   [+0, +4KB)         ws_pc  : 512 x {cm, pe}
   [+4KB, +1KB)       ws_e   : 256 entropy partials
   [+1KB, +16B)       ws_cnt : done-counter (zeroed by KA each call)        */
#define C_BYTES  ((size_t)NPARTS * KSZ * 4)
#define PC_OFF   C_BYTES
#define E_OFF    (PC_OFF + 4096)
#define CNT_OFF  (E_OFF + 1024)

// ---------------------------------------------------------------------------
// KA: 512 blocks x 512 threads (8 waves), 16 tokens/block.
// Per token: 32 lanes. proj (f32 partial + f64 5-step butterfly) -> indices,
// h->LDS, cm/pe partials, out = sign(h) @ w_out + b_out (w_out from L2),
// factor vectors A[64],B[128], 16-token partial C -> ws_C (coalesced).
// ---------------------------------------------------------------------------
__global__ __launch_bounds__(512) void ka_fused(const float* __restrict__ x,
                                                const float* __restrict__ w_in,
                                                const float* __restrict__ b_in,
                                                const float* __restrict__ w_out,
                                                const float* __restrict__ b_out,
                                                float* __restrict__ ws_C,
                                                float* __restrict__ ws_pc,
                                                unsigned int* __restrict__ ws_cnt,
                                                float* __restrict__ outv,
                                                float* __restrict__ out_ind) {
  __shared__ __align__(16) float s_winT[CD * DIMV];  // [c][d], transposed
  __shared__ float sh[TPB][CD];                      // h per token
  __shared__ __align__(16) float sA[TPB][4][16];     // [tok][khi&3][khi>>2]
  __shared__ __align__(16) float sB[TPB][128];       // [tok][klo]
  __shared__ float s_cm[TPB], s_pe[TPB];
  int t = threadIdx.x;

  if (blockIdx.x == 0 && t == 0) *ws_cnt = 0u;       // reset KB's counter

  // stage w_in transposed: one pass, thread t == column d
  {
    int d = t;
#pragma unroll
    for (int c = 0; c < CD; ++c) s_winT[c * DIMV + d] = w_in[d * CD + c];
  }
  __syncthreads();

  int lane = t & 63;
  int wave = t >> 6;          // 0..7
  int l31 = lane & 31;
  int grp = lane >> 5;        // 0..1
  int tok = wave * 2 + grp;   // 0..15
  int n = blockIdx.x * TPB + tok;

  const float4* x4 = (const float4*)(x + (size_t)n * DIMV);

  // per-lane f32 partial over 16 elements of d
  float facc[CD];
#pragma unroll
  for (int c = 0; c < CD; ++c) facc[c] = 0.f;
#pragma unroll
  for (int j = 0; j < 4; ++j) {
    float4 xv = x4[l31 + j * 32];
    int dbase = (l31 + j * 32) * 4;
#pragma unroll
    for (int c = 0; c < CD; ++c) {
      const float4 wv = *(const float4*)&s_winT[c * DIMV + dbase];
      facc[c] += xv.x * wv.x + xv.y * wv.y + xv.z * wv.z + xv.w * wv.w;
    }
  }
  // f64 butterfly across the 32-lane group
  double acc[CD];
#pragma unroll
  for (int c = 0; c < CD; ++c) {
    double a = (double)facc[c];
    a += __shfl_xor(a, 1, 64);
    a += __shfl_xor(a, 2, 64);
    a += __shfl_xor(a, 4, 64);
    a += __shfl_xor(a, 8, 64);
    a += __shfl_xor(a, 16, 64);
    acc[c] = a + (double)b_in[c];
  }

  // index
  int idx = 0;
#pragma unroll
  for (int c = 0; c < CD; ++c) idx |= (acc[c] > 0.0 ? 1 : 0) << (12 - c);
  if (l31 == 0) out_ind[n] = (float)idx;

  // lane l31 owns channel c==l31: h -> LDS, commit + entropy partials
  float hv = 0.f;
#pragma unroll
  for (int c = 0; c < CD; ++c) if (l31 == c) hv = (float)acc[c];
  float cm = 0.f, pe = 0.f;
  if (l31 < CD) {
    sh[tok][l31] = hv;
    float a = fabsf(hv);
    float d1 = a - 1.f;
    cm = d1 * d1;                       // (h - sign(h))^2 == (|h|-1)^2
    float z = 4.f * a;                  // binary entropy of sigmoid(4h)
    float e = expf(-z);
    pe = log1pf(e) + z * e / (1.f + e);
  }
  cm += __shfl_xor(cm, 1, 64); pe += __shfl_xor(pe, 1, 64);
  cm += __shfl_xor(cm, 2, 64); pe += __shfl_xor(pe, 2, 64);
  cm += __shfl_xor(cm, 4, 64); pe += __shfl_xor(pe, 4, 64);
  cm += __shfl_xor(cm, 8, 64); pe += __shfl_xor(pe, 8, 64);
  cm += __shfl_xor(cm, 16, 64); pe += __shfl_xor(pe, 16, 64);
  if (l31 == 0) { s_cm[tok] = cm; s_pe[tok] = pe; }

  // out = sign(h) @ w_out + b_out; c-outer, wave covers its 2 tokens
  int dpos = lane * 4;
  int id2[2];
  id2[0] = __shfl(idx, 0, 64);
  id2[1] = __shfl(idx, 32, 64);
  float4 o[2][2];
  {
    float4 bo0 = *(const float4*)(b_out + dpos);
    float4 bo1 = *(const float4*)(b_out + dpos + 256);
#pragma unroll
    for (int tt = 0; tt < 2; ++tt) { o[tt][0] = bo0; o[tt][1] = bo1; }
  }
#pragma unroll
  for (int c = 0; c < CD; ++c) {
    const float4 w0 = *(const float4*)&w_out[c * DIMV + dpos];
    const float4 w1 = *(const float4*)&w_out[c * DIMV + dpos + 256];
#pragma unroll
    for (int tt = 0; tt < 2; ++tt) {
      float sgn = ((id2[tt] >> (12 - c)) & 1) ? 1.f : -1.f;
      o[tt][0].x = fmaf(sgn, w0.x, o[tt][0].x);
      o[tt][0].y = fmaf(sgn, w0.y, o[tt][0].y);
      o[tt][0].z = fmaf(sgn, w0.z, o[tt][0].z);
      o[tt][0].w = fmaf(sgn, w0.w, o[tt][0].w);
      o[tt][1].x = fmaf(sgn, w1.x, o[tt][1].x);
      o[tt][1].y = fmaf(sgn, w1.y, o[tt][1].y);
      o[tt][1].z = fmaf(sgn, w1.z, o[tt][1].z);
      o[tt][1].w = fmaf(sgn, w1.w, o[tt][1].w);
    }
  }
  int n0 = blockIdx.x * TPB + wave * 2;
#pragma unroll
  for (int tt = 0; tt < 2; ++tt) {
    float4* dst = (float4*)(outv + (size_t)(n0 + tt) * DIMV);
    dst[lane] = o[tt][0];
    dst[lane + 64] = o[tt][1];
  }

  __syncthreads();                       // sh + s_cm/s_pe complete
  if (t == 0) {
    float C = 0.f, P = 0.f;
#pragma unroll
    for (int i = 0; i < TPB; ++i) { C += s_cm[i]; P += s_pe[i]; }
    ws_pc[blockIdx.x * 2] = C;
    ws_pc[blockIdx.x * 2 + 1] = P;
  }

  // ---- factors: each wave its 2 tokens; lane = khi ----
#pragma unroll
  for (int mm = 0; mm < 2; ++mm) {
    int m = wave * 2 + mm;
    float p[CD], q[CD];
#pragma unroll
    for (int c = 0; c < CD; ++c) {
      float hvv = sh[m][c];
      float e = expf(-4.f * hvv);
      float r = 1.f / (1.f + e);
      p[c] = r;                         // P(bit c = 1)
      q[c] = e * r;                     // P(bit c = 0)
    }
    float A = ((lane >> 5) & 1) ? p[0] : q[0];
    A *= ((lane >> 4) & 1) ? p[1] : q[1];
    A *= ((lane >> 3) & 1) ? p[2] : q[2];
    A *= ((lane >> 2) & 1) ? p[3] : q[3];
    A *= ((lane >> 1) & 1) ? p[4] : q[4];
    A *= (lane & 1) ? p[5] : q[5];
    sA[m][lane & 3][lane >> 2] = A;     // khi = lane
    float Bb = ((lane >> 5) & 1) ? p[7] : q[7];
    Bb *= ((lane >> 4) & 1) ? p[8] : q[8];
    Bb *= ((lane >> 3) & 1) ? p[9] : q[9];
    Bb *= ((lane >> 2) & 1) ? p[10] : q[10];
    Bb *= ((lane >> 1) & 1) ? p[11] : q[11];
    Bb *= (lane & 1) ? p[12] : q[12];
    sB[m][lane] = q[6] * Bb;            // klo = lane      (bit6 = 0)
    sB[m][64 + lane] = p[6] * Bb;       // klo = lane + 64 (bit6 = 1)
  }
  __syncthreads();

  // ---- outer product: slot s = t + 512*j = khi*128+klo,
  //      klo = t&127 (per-lane), khi = (t>>7) + 4*j (uniform float4 reads) --
  int c2 = t >> 7;                      // 0..3
  int klo = t & 127;
  float acc2[16];
#pragma unroll
  for (int j = 0; j < 16; ++j) acc2[j] = 0.f;
  for (int m = 0; m < TPB; ++m) {
    float Bv = sB[m][klo];
    const float4* A4 = (const float4*)&sA[m][c2][0];  // wave-uniform
#pragma unroll
    for (int jj = 0; jj < 4; ++jj) {
      float4 a = A4[jj];
      acc2[jj * 4 + 0] = fmaf(a.x, Bv, acc2[jj * 4 + 0]);
      acc2[jj * 4 + 1] = fmaf(a.y, Bv, acc2[jj * 4 + 1]);
      acc2[jj * 4 + 2] = fmaf(a.z, Bv, acc2[jj * 4 + 2]);
      acc2[jj * 4 + 3] = fmaf(a.w, Bv, acc2[jj * 4 + 3]);
    }
  }
  float* dst = ws_C + (size_t)blockIdx.x * KSZ;
#pragma unroll
  for (int j = 0; j < 16; ++j) dst[t + 512 * j] = acc2[j];  // coalesced
}

// ---------------------------------------------------------------------------
// KB: reduce NPARTS partial C's -> 256 entropy partials; the LAST block
// (device atomic counter, zeroed by KA) assembles aux (fixed-order sums ->
// deterministic regardless of which block finishes last).
// ---------------------------------------------------------------------------
__global__ __launch_bounds__(256) void kb_final(const float* __restrict__ ws_C,
                                                const float* __restrict__ ws_pc,
                                                float* __restrict__ ws_e,
                                                unsigned int* __restrict__ ws_cnt,
                                                float* __restrict__ d_aux) {
  __shared__ float red[256];
  __shared__ int s_last;
  int t = threadIdx.x;
  int sl = t & 31, pg = t >> 5;
  int s = blockIdx.x * 32 + sl;
  float a0 = 0.f, a1 = 0.f, a2 = 0.f, a3 = 0.f;
  for (int i = 0; i < 64; i += 4) {
    a0 += ws_C[(size_t)(pg + 8 * (i + 0)) * KSZ + s];
    a1 += ws_C[(size_t)(pg + 8 * (i + 1)) * KSZ + s];
    a2 += ws_C[(size_t)(pg + 8 * (i + 2)) * KSZ + s];
    a3 += ws_C[(size_t)(pg + 8 * (i + 3)) * KSZ + s];
  }
  red[t] = (a0 + a1) + (a2 + a3);
  __syncthreads();
  float contrib = 0.f;
  if (t < 32) {
    float v = red[t];
#pragma unroll
    for (int j = 1; j < 8; ++j) v += red[t + 32 * j];
    float avg = v * (1.f / (float)NTOK);
    contrib = -avg * logf(avg + 1e-5f);
  }
  if (t < 64) {
    contrib += __shfl_xor(contrib, 1, 64);
    contrib += __shfl_xor(contrib, 2, 64);
    contrib += __shfl_xor(contrib, 4, 64);
    contrib += __shfl_xor(contrib, 8, 64);
    contrib += __shfl_xor(contrib, 16, 64);
    if (t == 0) ws_e[blockIdx.x] = contrib;
  }
  // last-block-done: release store above, device-scope counter
  if (t == 0) {
    __threadfence();
    unsigned int old = atomicAdd(ws_cnt, 1u);
    s_last = (old == 255u) ? 1 : 0;
  }
  __syncthreads();
  if (s_last) {
    __threadfence();                    // acquire: see all ws_e / ws_pc
    __shared__ float rc[256], rp[256], re[256];
    float cm2 = 0.f, pe2 = 0.f;
    for (int i = t; i < 512; i += 256) {
      cm2 += ws_pc[2 * i];
      pe2 += ws_pc[2 * i + 1];
    }
    rc[t] = cm2; rp[t] = pe2; re[t] = ws_e[t];
    __syncthreads();
    if (t < 64) {
      float C = rc[t] + rc[t + 64] + rc[t + 128] + rc[t + 192];
      float P = rp[t] + rp[t + 64] + rp[t + 128] + rp[t + 192];
      float E = re[t] + re[t + 64] + re[t + 128] + re[t + 192];
      C += __shfl_xor(C, 1, 64); P += __shfl_xor(P, 1, 64); E += __shfl_xor(E, 1, 64);
      C += __shfl_xor(C, 2, 64); P += __shfl_xor(P, 2, 64); E += __shfl_xor(E, 2, 64);
      C += __shfl_xor(C, 4, 64); P += __shfl_xor(P, 4, 64); E += __shfl_xor(E, 4, 64);
      C += __shfl_xor(C, 8, 64); P += __shfl_xor(P, 8, 64); E += __shfl_xor(E, 8, 64);
      C += __shfl_xor(C, 16, 64); P += __shfl_xor(P, 16, 64); E += __shfl_xor(E, 16, 64);
      C += __shfl_xor(C, 32, 64); P += __shfl_xor(P, 32, 64); E += __shfl_xor(E, 32, 64);
      if (t == 0) {
        float commit = C * (1.f / (float)(NTOK * CD));
        float psE = P * (1.f / (float)NTOK);
        d_aux[0] = 0.1f * (psE - E) + 0.25f * commit;
      }
    }
  }
}

extern "C" void kernel_launch(void* const* d_in, const int* in_sizes, int n_in,
                              void* d_out, int out_size, void* d_ws, size_t ws_size,
                              hipStream_t stream) {
  const float* x     = (const float*)d_in[0];
  const float* w_in  = (const float*)d_in[1];
  const float* b_in  = (const float*)d_in[2];
  const float* w_out = (const float*)d_in[3];
  const float* b_out = (const float*)d_in[4];
  // d_in[5] = codebook (unused: codes are the 13-bit sign patterns)

  float* outv = (float*)d_out;                       // [4*2048*512]
  float* ind  = outv + (size_t)NTOK * DIMV;          // [8192] as float
  float* aux  = ind + NTOK;                          // [1]

  float*        ws_C   = (float*)d_ws;
  float*        ws_pc  = (float*)((char*)d_ws + PC_OFF);
  float*        ws_e   = (float*)((char*)d_ws + E_OFF);
  unsigned int* ws_cnt = (unsigned int*)((char*)d_ws + CNT_OFF);

  ka_fused<<<NPARTS, 512, 0, stream>>>(x, w_in, b_in, w_out, b_out,
                                       ws_C, ws_pc, ws_cnt, outv, ind);
  kb_final<<<256, 256, 0, stream>>>(ws_C, ws_pc, ws_e, ws_cnt, aux);
}